// Round 1
// 437.200 us; speedup vs baseline: 1.0021x; 1.0021x over previous
//
#include <hip/hip_runtime.h>

// Block-diagonal transform via MFMA f16 + per-row dynamic int8 quant.
// R[1M x 64] = X[1M x 64] @ H[64 x 64]; original row = 128 X-chunks.
// v2 changes vs 438us baseline:
//  * operand-swapped MFMA: D = H^T_tile * X^T_tile, so D.col=chunk (lane&15),
//    D.row=output col (quad*4+i) -> epilogue is 8x global_store_dwordx4
//    per lane (was 32x scalar store_dword).
//  * ROWS=4 rows per block (grid 2048) with register prefetch of the next
//    row's x while current row computes/stores.
//  * raw s_barrier + lgkmcnt(0) (no vmcnt drain) so prefetch loads stay in
//    flight across the per-row barrier (__syncthreads would drain vmcnt).
//  * h staged once per block into LDS as transposed f16 (stride 72 halves =
//    144B: 16B-aligned for ds_read_b128, ~2-way banks) -> frees 32 VGPRs,
//    keeps total ~110 VGPR under the 128 cap of __launch_bounds__(256,4).

typedef _Float16 half8_t __attribute__((ext_vector_type(8)));
typedef float float4_t __attribute__((ext_vector_type(4)));
typedef int int4_t __attribute__((ext_vector_type(4)));

constexpr int Ncols  = 8192;
constexpr int Kdim   = 64;
constexpr int NWAVES = 4;
constexpr int ROWS   = 4;   // original rows per block
constexpr int HPAD   = 72;  // halves per hT row (144B stride)

#define LDS_BARRIER() do {                                   \
    asm volatile("s_waitcnt lgkmcnt(0)" ::: "memory");       \
    __builtin_amdgcn_s_barrier();                            \
    asm volatile("" ::: "memory");                           \
} while (0)

__global__ __launch_bounds__(256, 4)
void bdq_mfma2(const float* __restrict__ x,
               const float* __restrict__ h,
               int* __restrict__ out)
{
    __shared__ __align__(16) _Float16 hT[Kdim * HPAD];  // hT[col][k], f16, padded
    __shared__ float swmax[2][NWAVES];                  // double-buffered per row

    const int tid    = threadIdx.x;
    const int lane   = tid & 63;
    const int wave   = tid >> 6;
    const int quad   = lane >> 4;   // 0..3
    const int l16    = lane & 15;
    const int chunk0 = wave * 32;   // first chunk owned by this wave
    const size_t row0 = (size_t)blockIdx.x * ROWS;

    const float* xr = x + row0 * Ncols;

    // ---- issue x prefetch for row 0: 8 x dwordx4 per lane ----
    float4 P[2][2][2];
#pragma unroll
    for (int rt = 0; rt < 2; ++rt)
#pragma unroll
        for (int ks = 0; ks < 2; ++ks) {
            const float* p = xr + (chunk0 + rt * 16 + l16) * Kdim + ks * 32 + quad * 8;
            P[rt][ks][0] = ((const float4*)p)[0];
            P[rt][ks][1] = ((const float4*)p)[1];
        }

    // ---- stage h -> LDS as transposed f16 (one time per block) ----
    {
        const int kk = tid >> 2;         // k row of h: 0..63
        const int c0 = (tid & 3) << 4;   // col group base: 0/16/32/48
        const float* hp = h + kk * Kdim + c0;
        float4 v[4];
#pragma unroll
        for (int i = 0; i < 4; ++i) v[i] = ((const float4*)hp)[i];
#pragma unroll
        for (int i = 0; i < 4; ++i) {
            hT[(c0 + i * 4 + 0) * HPAD + kk] = (_Float16)v[i].x;
            hT[(c0 + i * 4 + 1) * HPAD + kk] = (_Float16)v[i].y;
            hT[(c0 + i * 4 + 2) * HPAD + kk] = (_Float16)v[i].z;
            hT[(c0 + i * 4 + 3) * HPAD + kk] = (_Float16)v[i].w;
        }
    }
    LDS_BARRIER();   // hT visible; row-0 x loads stay in flight (no vmcnt drain)

#pragma unroll
    for (int r = 0; r < ROWS; ++r) {
        // ---- convert prefetched x to f16 fragments (waits vmcnt on P) ----
        half8_t af[2][2];
#pragma unroll
        for (int rt = 0; rt < 2; ++rt)
#pragma unroll
            for (int ks = 0; ks < 2; ++ks) {
                half8_t a;
                a[0] = (_Float16)P[rt][ks][0].x;
                a[1] = (_Float16)P[rt][ks][0].y;
                a[2] = (_Float16)P[rt][ks][0].z;
                a[3] = (_Float16)P[rt][ks][0].w;
                a[4] = (_Float16)P[rt][ks][1].x;
                a[5] = (_Float16)P[rt][ks][1].y;
                a[6] = (_Float16)P[rt][ks][1].z;
                a[7] = (_Float16)P[rt][ks][1].w;
                af[rt][ks] = a;
            }

        // ---- issue prefetch for next row (hides HBM latency under compute) ----
        if (r + 1 < ROWS) {
            const float* xn = xr + Ncols;
#pragma unroll
            for (int rt = 0; rt < 2; ++rt)
#pragma unroll
                for (int ks = 0; ks < 2; ++ks) {
                    const float* p = xn + (chunk0 + rt * 16 + l16) * Kdim + ks * 32 + quad * 8;
                    P[rt][ks][0] = ((const float4*)p)[0];
                    P[rt][ks][1] = ((const float4*)p)[1];
                }
        }

        // ---- MFMA, operand-swapped: D.row = out col, D.col = chunk ----
        float4_t acc[2][4];
#pragma unroll
        for (int rt = 0; rt < 2; ++rt)
#pragma unroll
            for (int ct = 0; ct < 4; ++ct)
                acc[rt][ct] = (float4_t){0.f, 0.f, 0.f, 0.f};

#pragma unroll
        for (int ks = 0; ks < 2; ++ks)
#pragma unroll
            for (int ct = 0; ct < 4; ++ct) {
                // A operand: A[row=l16 -> outcol ct*16+l16][k=quad*8+j]
                const half8_t hf =
                    *(const half8_t*)&hT[(ct * 16 + l16) * HPAD + ks * 32 + quad * 8];
#pragma unroll
                for (int rt = 0; rt < 2; ++rt)
                    acc[rt][ct] = __builtin_amdgcn_mfma_f32_16x16x32_f16(
                        hf, af[rt][ks], acc[rt][ct], 0, 0, 0);
            }

        // ---- row absmax: lane-local -> wave shfl -> cross-wave via LDS ----
        float lmax = 0.0f;
#pragma unroll
        for (int rt = 0; rt < 2; ++rt)
#pragma unroll
            for (int ct = 0; ct < 4; ++ct)
#pragma unroll
                for (int i = 0; i < 4; ++i)
                    lmax = fmaxf(lmax, fabsf(acc[rt][ct][i]));
#pragma unroll
        for (int off = 32; off > 0; off >>= 1)
            lmax = fmaxf(lmax, __shfl_xor(lmax, off, 64));
        if (lane == 0) swmax[r & 1][wave] = lmax;
        LDS_BARRIER();   // no vmcnt drain: next-row x loads remain outstanding
        const float rmax = fmaxf(fmaxf(swmax[r & 1][0], swmax[r & 1][1]),
                                 fmaxf(swmax[r & 1][2], swmax[r & 1][3]));
        const float inv = (rmax > 0.f) ? (127.0f / rmax) : 0.0f;  // zero row -> 0

        // ---- quant + vector store: lane holds 4 consecutive cols ----
        int* orow = out + (row0 + r) * Ncols;
#pragma unroll
        for (int rt = 0; rt < 2; ++rt) {
            const int cbase = (chunk0 + rt * 16 + l16) * Kdim;
#pragma unroll
            for (int ct = 0; ct < 4; ++ct) {
                int4_t q;
#pragma unroll
                for (int i = 0; i < 4; ++i) {
                    float v = rintf(acc[rt][ct][i] * inv);   // half-even = np.round
                    v = fminf(fmaxf(v, -128.f), 127.f);
                    q[i] = (int)v;
                }
                *(int4_t*)(orow + cbase + ct * 16 + quad * 4) = q;
            }
        }

        xr += Ncols;
    }
}

extern "C" void kernel_launch(void* const* d_in, const int* in_sizes, int n_in,
                              void* d_out, int out_size, void* d_ws, size_t ws_size,
                              hipStream_t stream) {
    const float* x = (const float*)d_in[0];   // [8192, 8192]
    const float* h = (const float*)d_in[1];   // [64, 64]
    int* out = (int*)d_out;                   // int8 values as int32
    dim3 grid(8192 / ROWS), block(256);
    hipLaunchKernelGGL(bdq_mfma2, grid, block, 0, stream, x, h, out);
}